// Round 7
// baseline (216.662 us; speedup 1.0000x reference)
//
#include <hip/hip_runtime.h>
#include <hip/hip_bf16.h>

#define B_ 2
#define T_ 2048
#define C_ 1024
#define H_ 16
#define D_ 64
#define M_ (B_*T_)          // 4096 rows
#define SCALE_ 0.125f       // 1/sqrt(64)
#define NEG_ (-1e30f)

typedef __bf16 bf16;
typedef __bf16 bf16x8 __attribute__((ext_vector_type(8)));
typedef float  f32x4  __attribute__((ext_vector_type(4)));

__device__ __forceinline__ bf16x8 cvt8(f32x4 a, f32x4 b) {
  bf16x8 r;
  #pragma unroll
  for (int i = 0; i < 4; ++i) { r[i] = (bf16)a[i]; r[i+4] = (bf16)b[i]; }
  return r;
}

// ---------------------------------------------------------------------------
// NT GEMM (MFMA): C[m,n] = sum_k A[m,k] * W[n,k]. 128x128 tile, BK=32, 4 waves.
// W is f32 (converted to bf16 at staging).
// OUTMODE 0: A = f32 x; OUT = bf16 [B,H,T,D] (QKV; blockIdx.z selects W/O)
// OUTMODE 1: A = bf16 ao; OUT = f32 [M,C]  (final output)
// ---------------------------------------------------------------------------
#define LDK 40

template<int OUTMODE>
__global__ __launch_bounds__(256)
void gemm_nt(const void* __restrict__ Av,
             const float* __restrict__ W0, const float* __restrict__ W1,
             const float* __restrict__ W2,
             void* __restrict__ O0v, void* __restrict__ O1v, void* __restrict__ O2v,
             int K) {
  __shared__ __align__(16) bf16 As[128*LDK];
  __shared__ __align__(16) bf16 Bs[128*LDK];

  const float* W = W0;
  void* Ov = O0v;
  if constexpr (OUTMODE == 0) {
    if (blockIdx.z == 1)      { W = W1; Ov = O1v; }
    else if (blockIdx.z == 2) { W = W2; Ov = O2v; }
  }

  const int m0 = blockIdx.y * 128, n0 = blockIdx.x * 128;
  const int tid = threadIdx.x, wid = tid >> 6, lane = tid & 63;
  const int wm = wid >> 1, wn = wid & 1;

  f32x4 acc[4][4] = {};

  // staging: thread t -> rows (t>>2), (t>>2)+64; k-chunk (t&3)*8
  const int sr = tid >> 2, skc = tid & 3;
  const float* Bg = W + (size_t)(n0 + sr) * K + skc*8;

  const float* AgF = nullptr; const bf16* AgH = nullptr;
  if constexpr (OUTMODE == 0) AgF = (const float*)Av + (size_t)(m0 + sr) * K + skc*8;
  else                        AgH = (const bf16*)Av  + (size_t)(m0 + sr) * K + skc*8;

  const int amRow = wm*64 + (lane & 15);
  const int bnRow = wn*64 + (lane & 15);
  const int kSlot = (lane >> 4) * 8;

  for (int k0 = 0; k0 < K; k0 += 32) {
    bf16x8 a0, a1;
    if constexpr (OUTMODE == 0) {
      a0 = cvt8(*(const f32x4*)(AgF + k0),
                *(const f32x4*)(AgF + k0 + 4));
      a1 = cvt8(*(const f32x4*)(AgF + (size_t)64*K + k0),
                *(const f32x4*)(AgF + (size_t)64*K + k0 + 4));
    } else {
      a0 = *(const bf16x8*)(AgH + k0);
      a1 = *(const bf16x8*)(AgH + (size_t)64*K + k0);
    }
    bf16x8 b0 = cvt8(*(const f32x4*)(Bg + k0),
                     *(const f32x4*)(Bg + k0 + 4));
    bf16x8 b1 = cvt8(*(const f32x4*)(Bg + (size_t)64*K + k0),
                     *(const f32x4*)(Bg + (size_t)64*K + k0 + 4));

    __syncthreads();
    *(bf16x8*)(As + sr*LDK        + skc*8) = a0;
    *(bf16x8*)(As + (sr+64)*LDK   + skc*8) = a1;
    *(bf16x8*)(Bs + sr*LDK        + skc*8) = b0;
    *(bf16x8*)(Bs + (sr+64)*LDK   + skc*8) = b1;
    __syncthreads();

    bf16x8 af[4], bfr[4];
    #pragma unroll
    for (int i = 0; i < 4; ++i) {
      af[i]  = *(const bf16x8*)(As + (amRow + i*16)*LDK + kSlot);
      bfr[i] = *(const bf16x8*)(Bs + (bnRow + i*16)*LDK + kSlot);
    }
    #pragma unroll
    for (int i = 0; i < 4; ++i)
      #pragma unroll
      for (int j = 0; j < 4; ++j)
        acc[i][j] = __builtin_amdgcn_mfma_f32_16x16x32_bf16(af[i], bfr[j], acc[i][j], 0, 0, 0);
  }

  // epilogue: C/D layout col=lane&15, row=(lane>>4)*4+reg
  const int rBase = m0 + wm*64 + (lane >> 4) * 4;
  const int cBase = n0 + wn*64 + (lane & 15);
  #pragma unroll
  for (int fm = 0; fm < 4; ++fm) {
    #pragma unroll
    for (int fn = 0; fn < 4; ++fn) {
      #pragma unroll
      for (int j = 0; j < 4; ++j) {
        int m = rBase + fm*16 + j;
        int n = cBase + fn*16;
        if constexpr (OUTMODE == 0) {
          int b = m >> 11, t = m & 2047, h = n >> 6, d = n & 63;
          ((bf16*)Ov)[((size_t)(b*H_ + h) * T_ + t) * D_ + d] = (bf16)acc[fm][fn][j];
        } else {
          ((float*)Ov)[(size_t)m * C_ + n] = acc[fm][fn][j];   // f32 final output
        }
      }
    }
  }
}

// ---------------------------------------------------------------------------
// Flash attention, causal (round-3 structure, symbolically re-verified).
// One block = one (b,h) x 64 q-rows, 4 waves x 16 q-rows, KV tiles of 64.
// Q/K/V bf16 [B,H,T,D]; output bf16 [B,T,C].
// ---------------------------------------------------------------------------
#define LKV 72

__global__ __launch_bounds__(256)
void attn_fwd(const bf16* __restrict__ Q, const bf16* __restrict__ Km,
              const bf16* __restrict__ V, bf16* __restrict__ Oa) {
  __shared__ __align__(16) bf16 Ks [64*LKV];   // [kv][d]
  __shared__ __align__(16) bf16 Vts[64*LKV];   // [d][kv] (transposed)
  __shared__ __align__(16) bf16 Ps [64*LKV];   // [q][kv]

  const int bh = blockIdx.y;
  const int qt = blockIdx.x;
  const int q0 = qt * 64;
  const int tid = threadIdx.x, wid = tid >> 6, lane = tid & 63;

  const bf16* Qb = Q  + (size_t)bh * T_ * D_;
  const bf16* Kb = Km + (size_t)bh * T_ * D_;
  const bf16* Vb = V  + (size_t)bh * T_ * D_;

  const int qrow = q0 + wid*16 + (lane & 15);
  bf16x8 aq0 = *(const bf16x8*)(Qb + (size_t)qrow*64 +      (lane >> 4)*8);
  bf16x8 aq1 = *(const bf16x8*)(Qb + (size_t)qrow*64 + 32 + (lane >> 4)*8);

  f32x4 oacc[4] = {};
  float m_r[4], l_r[4];
  #pragma unroll
  for (int j = 0; j < 4; ++j) { m_r[j] = NEG_; l_r[j] = 0.f; }

  const int ksr = tid >> 3, kskc = tid & 7;
  const int myrow4 = (lane >> 4) * 4;
  const int qg = q0 + wid*16 + myrow4;
  const int kSlot = (lane >> 4) * 8;

  for (int kt = 0; kt <= qt; ++kt) {
    const int kv0 = kt * 64;

    bf16x8 kv_a = *(const bf16x8*)(Kb + (size_t)(kv0 + ksr)*64      + kskc*8);
    bf16x8 kv_b = *(const bf16x8*)(Kb + (size_t)(kv0 + ksr + 32)*64 + kskc*8);
    bf16x8 vv0  = *(const bf16x8*)(Vb + (size_t)(kv0 + lane)*64 + (wid  )*8);
    bf16x8 vv1  = *(const bf16x8*)(Vb + (size_t)(kv0 + lane)*64 + (wid+4)*8);

    __syncthreads();

    *(bf16x8*)(Ks + ksr*LKV      + kskc*8) = kv_a;
    *(bf16x8*)(Ks + (ksr+32)*LKV + kskc*8) = kv_b;
    #pragma unroll
    for (int jj = 0; jj < 8; ++jj) {
      Vts[((wid  )*8 + jj)*LKV + lane] = vv0[jj];
      Vts[((wid+4)*8 + jj)*LKV + lane] = vv1[jj];
    }
    __syncthreads();

    // S = Q K^T
    f32x4 s[4];
    #pragma unroll
    for (int n = 0; n < 4; ++n) {
      int row = n*16 + (lane & 15);
      bf16x8 bk0 = *(const bf16x8*)(Ks + row*LKV      + kSlot);
      bf16x8 bk1 = *(const bf16x8*)(Ks + row*LKV + 32 + kSlot);
      f32x4 a = {};
      a = __builtin_amdgcn_mfma_f32_16x16x32_bf16(aq0, bk0, a, 0, 0, 0);
      a = __builtin_amdgcn_mfma_f32_16x16x32_bf16(aq1, bk1, a, 0, 0, 0);
      s[n] = a;
    }

    // online softmax
    #pragma unroll
    for (int j = 0; j < 4; ++j) {
      float pm = NEG_;
      #pragma unroll
      for (int n = 0; n < 4; ++n) {
        int kvg = kv0 + n*16 + (lane & 15);
        float sv = (kvg <= qg + j) ? s[n][j] * SCALE_ : NEG_;
        s[n][j] = sv;
        pm = fmaxf(pm, sv);
      }
      pm = fmaxf(pm, __shfl_xor(pm, 1));
      pm = fmaxf(pm, __shfl_xor(pm, 2));
      pm = fmaxf(pm, __shfl_xor(pm, 4));
      pm = fmaxf(pm, __shfl_xor(pm, 8));
      float mnew = fmaxf(m_r[j], pm);
      float scold = __expf(m_r[j] - mnew);
      float ps = 0.f;
      #pragma unroll
      for (int n = 0; n < 4; ++n) {
        float p = __expf(s[n][j] - mnew);
        s[n][j] = p;
        ps += p;
      }
      ps += __shfl_xor(ps, 1);
      ps += __shfl_xor(ps, 2);
      ps += __shfl_xor(ps, 4);
      ps += __shfl_xor(ps, 8);
      l_r[j] = l_r[j] * scold + ps;
      m_r[j] = mnew;
      #pragma unroll
      for (int n = 0; n < 4; ++n) oacc[n][j] *= scold;
    }

    // P -> LDS, barrier, PV
    #pragma unroll
    for (int n = 0; n < 4; ++n) {
      #pragma unroll
      for (int j = 0; j < 4; ++j) {
        int prow = wid*16 + myrow4 + j;
        Ps[prow*LKV + n*16 + (lane & 15)] = (bf16)s[n][j];
      }
    }
    __syncthreads();

    int parow = wid*16 + (lane & 15);
    bf16x8 pa0 = *(const bf16x8*)(Ps + parow*LKV      + kSlot);
    bf16x8 pa1 = *(const bf16x8*)(Ps + parow*LKV + 32 + kSlot);
    #pragma unroll
    for (int n = 0; n < 4; ++n) {
      int vrow = n*16 + (lane & 15);
      bf16x8 bv0 = *(const bf16x8*)(Vts + vrow*LKV      + kSlot);
      bf16x8 bv1 = *(const bf16x8*)(Vts + vrow*LKV + 32 + kSlot);
      oacc[n] = __builtin_amdgcn_mfma_f32_16x16x32_bf16(pa0, bv0, oacc[n], 0, 0, 0);
      oacc[n] = __builtin_amdgcn_mfma_f32_16x16x32_bf16(pa1, bv1, oacc[n], 0, 0, 0);
    }
  }

  // epilogue: O /= l -> bf16 [B,T,C]
  const int b = bh >> 4, h = bh & 15;
  const int tg = q0 + wid*16 + myrow4;
  #pragma unroll
  for (int n = 0; n < 4; ++n) {
    int ch = h*64 + n*16 + (lane & 15);
    #pragma unroll
    for (int j = 0; j < 4; ++j) {
      float o = oacc[n][j] / l_r[j];
      Oa[((size_t)(b*T_ + tg + j)) * C_ + ch] = (bf16)o;
    }
  }
}

// ---------------------------------------------------------------------------
extern "C" void kernel_launch(void* const* d_in, const int* in_sizes, int n_in,
                              void* d_out, int out_size, void* d_ws, size_t ws_size,
                              hipStream_t stream) {
  const float* x  = (const float*)d_in[0];   // ALL inputs f32
  const float* wq = (const float*)d_in[1];
  const float* wk = (const float*)d_in[2];
  const float* wv = (const float*)d_in[3];
  const float* wo = (const float*)d_in[4];

  bf16* q  = (bf16*)d_ws;                    // [B,H,T,D] bf16
  bf16* k  = q  + (size_t)M_ * C_;
  bf16* v  = k  + (size_t)M_ * C_;           // ws peak 25.2 MB (proven fits)
  bf16* aoStage = (bf16*)d_out;              // stage attn out in d_out (bf16, 8.4MB of 16.8MB)

  dim3 blk(256);
  // QKV projections: x(f32) @ W^T(f32) -> bf16 [B,H,T,D]
  gemm_nt<0><<<dim3(C_/128, M_/128, 3), blk, 0, stream>>>(x, wq, wk, wv, q, k, v, C_);
  // causal flash attention -> bf16 [B,T,C] staged in d_out
  attn_fwd<<<dim3(T_/64, B_*H_), blk, 0, stream>>>(q, k, v, aoStage);
  // move staged ao into ws (q region dead after attention)
  hipMemcpyAsync(q, aoStage, (size_t)M_ * C_ * sizeof(bf16),
                 hipMemcpyDeviceToDevice, stream);
  // output projection: ao(bf16) @ wo^T(f32) -> f32 d_out
  gemm_nt<1><<<dim3(C_/128, M_/128, 1), blk, 0, stream>>>(q, wo, nullptr, nullptr,
                                                          d_out, nullptr, nullptr, C_);
}

// Round 8
// 171.831 us; speedup vs baseline: 1.2609x; 1.2609x over previous
//
#include <hip/hip_runtime.h>
#include <hip/hip_bf16.h>

#define B_ 2
#define T_ 2048
#define C_ 1024
#define H_ 16
#define D_ 64
#define M_ (B_*T_)          // 4096 rows
#define SCALE_ 0.125f       // 1/sqrt(64)
#define NEG_ (-1e30f)

typedef __bf16 bf16;
typedef __bf16 bf16x8 __attribute__((ext_vector_type(8)));
typedef float  f32x4  __attribute__((ext_vector_type(4)));

__device__ __forceinline__ bf16x8 cvt8(f32x4 a, f32x4 b) {
  bf16x8 r;
  #pragma unroll
  for (int i = 0; i < 4; ++i) { r[i] = (bf16)a[i]; r[i+4] = (bf16)b[i]; }
  return r;
}

// ---------------------------------------------------------------------------
// NT GEMM (MFMA): C[m,n] = sum_k A[m,k] * W[n,k]. 128x128 tile, BK=32, 4 waves.
// OUTMODE 0: A = f32 x; OUT bf16; z=0,1 -> [B,H,T,D] (Q,K); z=2 -> [B,H,D,T] (V^T)
// OUTMODE 1: A = bf16 ao; OUT = f32 [M,C]  (final output)
// ---------------------------------------------------------------------------
#define LDK 40

template<int OUTMODE>
__global__ __launch_bounds__(256)
void gemm_nt(const void* __restrict__ Av,
             const float* __restrict__ W0, const float* __restrict__ W1,
             const float* __restrict__ W2,
             void* __restrict__ O0v, void* __restrict__ O1v, void* __restrict__ O2v,
             int K) {
  __shared__ __align__(16) bf16 As[128*LDK];
  __shared__ __align__(16) bf16 Bs[128*LDK];

  const float* W = W0;
  void* Ov = O0v;
  bool vtrans = false;
  if constexpr (OUTMODE == 0) {
    if (blockIdx.z == 1)      { W = W1; Ov = O1v; }
    else if (blockIdx.z == 2) { W = W2; Ov = O2v; vtrans = true; }
  }

  const int m0 = blockIdx.y * 128, n0 = blockIdx.x * 128;
  const int tid = threadIdx.x, wid = tid >> 6, lane = tid & 63;
  const int wm = wid >> 1, wn = wid & 1;

  f32x4 acc[4][4] = {};

  const int sr = tid >> 2, skc = tid & 3;
  const float* Bg = W + (size_t)(n0 + sr) * K + skc*8;

  const float* AgF = nullptr; const bf16* AgH = nullptr;
  if constexpr (OUTMODE == 0) AgF = (const float*)Av + (size_t)(m0 + sr) * K + skc*8;
  else                        AgH = (const bf16*)Av  + (size_t)(m0 + sr) * K + skc*8;

  const int amRow = wm*64 + (lane & 15);
  const int bnRow = wn*64 + (lane & 15);
  const int kSlot = (lane >> 4) * 8;

  for (int k0 = 0; k0 < K; k0 += 32) {
    bf16x8 a0, a1;
    if constexpr (OUTMODE == 0) {
      a0 = cvt8(*(const f32x4*)(AgF + k0),
                *(const f32x4*)(AgF + k0 + 4));
      a1 = cvt8(*(const f32x4*)(AgF + (size_t)64*K + k0),
                *(const f32x4*)(AgF + (size_t)64*K + k0 + 4));
    } else {
      a0 = *(const bf16x8*)(AgH + k0);
      a1 = *(const bf16x8*)(AgH + (size_t)64*K + k0);
    }
    bf16x8 b0 = cvt8(*(const f32x4*)(Bg + k0),
                     *(const f32x4*)(Bg + k0 + 4));
    bf16x8 b1 = cvt8(*(const f32x4*)(Bg + (size_t)64*K + k0),
                     *(const f32x4*)(Bg + (size_t)64*K + k0 + 4));

    __syncthreads();
    *(bf16x8*)(As + sr*LDK        + skc*8) = a0;
    *(bf16x8*)(As + (sr+64)*LDK   + skc*8) = a1;
    *(bf16x8*)(Bs + sr*LDK        + skc*8) = b0;
    *(bf16x8*)(Bs + (sr+64)*LDK   + skc*8) = b1;
    __syncthreads();

    bf16x8 af[4], bfr[4];
    #pragma unroll
    for (int i = 0; i < 4; ++i) {
      af[i]  = *(const bf16x8*)(As + (amRow + i*16)*LDK + kSlot);
      bfr[i] = *(const bf16x8*)(Bs + (bnRow + i*16)*LDK + kSlot);
    }
    #pragma unroll
    for (int i = 0; i < 4; ++i)
      #pragma unroll
      for (int j = 0; j < 4; ++j)
        acc[i][j] = __builtin_amdgcn_mfma_f32_16x16x32_bf16(af[i], bfr[j], acc[i][j], 0, 0, 0);
  }

  // epilogue: C/D layout col=lane&15, row=(lane>>4)*4+reg
  const int rBase = m0 + wm*64 + (lane >> 4) * 4;
  const int cBase = n0 + wn*64 + (lane & 15);
  #pragma unroll
  for (int fm = 0; fm < 4; ++fm) {
    #pragma unroll
    for (int fn = 0; fn < 4; ++fn) {
      #pragma unroll
      for (int j = 0; j < 4; ++j) {
        int m = rBase + fm*16 + j;
        int n = cBase + fn*16;
        if constexpr (OUTMODE == 0) {
          int b = m >> 11, t = m & 2047, h = n >> 6, d = n & 63;
          size_t idx = vtrans ? (((size_t)(b*H_ + h) * D_ + d) * T_ + t)    // V^T [B,H,D,T]
                              : (((size_t)(b*H_ + h) * T_ + t) * D_ + d);  // Q,K [B,H,T,D]
          ((bf16*)Ov)[idx] = (bf16)acc[fm][fn][j];
        } else {
          ((float*)Ov)[(size_t)m * C_ + n] = acc[fm][fn][j];   // f32 final output
        }
      }
    }
  }
}

// ---------------------------------------------------------------------------
// Flash attention, causal. Paired q-tiles for perfect balance: block qp does
// q-tiles {qp, 31-qp} -> every block runs exactly 33 kt-iterations.
// 4 waves x 16 q-rows. Q,K in [B,H,T,D]; V pre-transposed [B,H,D,T].
// Output bf16 [B,T,C].
// ---------------------------------------------------------------------------
#define LKV 72

__global__ __launch_bounds__(256)
void attn_fwd(const bf16* __restrict__ Q, const bf16* __restrict__ Km,
              const bf16* __restrict__ Vt, bf16* __restrict__ Oa) {
  __shared__ __align__(16) bf16 Ks [64*LKV];   // [kv][d]
  __shared__ __align__(16) bf16 Vts[64*LKV];   // [d][kv] (already transposed in gmem)
  __shared__ __align__(16) bf16 Ps [64*LKV];   // [q][kv] (wave-private rows)

  const int bh = blockIdx.y;
  const int qp = blockIdx.x;                   // 0..15
  const int tid = threadIdx.x, wid = tid >> 6, lane = tid & 63;

  const bf16* Qb = Q  + (size_t)bh * T_ * D_;
  const bf16* Kb = Km + (size_t)bh * T_ * D_;
  const bf16* Vb = Vt + (size_t)bh * D_ * T_;  // [D,T]

  const int ksr = tid >> 3, kskc = tid & 7;    // staging: rows ksr, ksr+32; chunk kskc
  const int myrow4 = (lane >> 4) * 4;
  const int kSlot = (lane >> 4) * 8;
  const int b = bh >> 4, h = bh & 15;

  for (int rep = 0; rep < 2; ++rep) {
    const int qt = rep ? (31 - qp) : qp;
    const int q0 = qt * 64;

    const int qrow = q0 + wid*16 + (lane & 15);
    bf16x8 aq0 = *(const bf16x8*)(Qb + (size_t)qrow*64 +      (lane >> 4)*8);
    bf16x8 aq1 = *(const bf16x8*)(Qb + (size_t)qrow*64 + 32 + (lane >> 4)*8);

    f32x4 oacc[4] = {};
    float m_r[4], l_r[4];
    #pragma unroll
    for (int j = 0; j < 4; ++j) { m_r[j] = NEG_; l_r[j] = 0.f; }

    const int qg = q0 + wid*16 + myrow4;

    for (int kt = 0; kt <= qt; ++kt) {
      const int kv0 = kt * 64;

      // prefetch K and V^T tiles to registers (both linear row copies now)
      bf16x8 kv_a = *(const bf16x8*)(Kb + (size_t)(kv0 + ksr)*64      + kskc*8);
      bf16x8 kv_b = *(const bf16x8*)(Kb + (size_t)(kv0 + ksr + 32)*64 + kskc*8);
      bf16x8 vt_a = *(const bf16x8*)(Vb + (size_t)(ksr     )*T_ + kv0 + kskc*8);
      bf16x8 vt_b = *(const bf16x8*)(Vb + (size_t)(ksr + 32)*T_ + kv0 + kskc*8);

      __syncthreads();   // previous iteration's LDS reads complete

      *(bf16x8*)(Ks  + ksr*LKV      + kskc*8) = kv_a;
      *(bf16x8*)(Ks  + (ksr+32)*LKV + kskc*8) = kv_b;
      *(bf16x8*)(Vts + ksr*LKV      + kskc*8) = vt_a;
      *(bf16x8*)(Vts + (ksr+32)*LKV + kskc*8) = vt_b;
      __syncthreads();

      // S = Q K^T
      f32x4 s[4];
      #pragma unroll
      for (int n = 0; n < 4; ++n) {
        int row = n*16 + (lane & 15);
        bf16x8 bk0 = *(const bf16x8*)(Ks + row*LKV      + kSlot);
        bf16x8 bk1 = *(const bf16x8*)(Ks + row*LKV + 32 + kSlot);
        f32x4 a = {};
        a = __builtin_amdgcn_mfma_f32_16x16x32_bf16(aq0, bk0, a, 0, 0, 0);
        a = __builtin_amdgcn_mfma_f32_16x16x32_bf16(aq1, bk1, a, 0, 0, 0);
        s[n] = a;
      }

      // online softmax (per 16-lane group; lane owns 4 rows via reg j)
      #pragma unroll
      for (int j = 0; j < 4; ++j) {
        float pm = NEG_;
        #pragma unroll
        for (int n = 0; n < 4; ++n) {
          int kvg = kv0 + n*16 + (lane & 15);
          float sv = (kvg <= qg + j) ? s[n][j] * SCALE_ : NEG_;
          s[n][j] = sv;
          pm = fmaxf(pm, sv);
        }
        pm = fmaxf(pm, __shfl_xor(pm, 1));
        pm = fmaxf(pm, __shfl_xor(pm, 2));
        pm = fmaxf(pm, __shfl_xor(pm, 4));
        pm = fmaxf(pm, __shfl_xor(pm, 8));
        float mnew = fmaxf(m_r[j], pm);
        float scold = __expf(m_r[j] - mnew);
        float ps = 0.f;
        #pragma unroll
        for (int n = 0; n < 4; ++n) {
          float p = __expf(s[n][j] - mnew);
          s[n][j] = p;
          ps += p;
        }
        ps += __shfl_xor(ps, 1);
        ps += __shfl_xor(ps, 2);
        ps += __shfl_xor(ps, 4);
        ps += __shfl_xor(ps, 8);
        l_r[j] = l_r[j] * scold + ps;
        m_r[j] = mnew;
        #pragma unroll
        for (int n = 0; n < 4; ++n) oacc[n][j] *= scold;
      }

      // P -> LDS (wave-private rows): wave-level wait suffices, no block barrier
      #pragma unroll
      for (int n = 0; n < 4; ++n) {
        #pragma unroll
        for (int j = 0; j < 4; ++j) {
          int prow = wid*16 + myrow4 + j;
          Ps[prow*LKV + n*16 + (lane & 15)] = (bf16)s[n][j];
        }
      }
      asm volatile("s_waitcnt lgkmcnt(0)" ::: "memory");
      __builtin_amdgcn_sched_barrier(0);

      int parow = wid*16 + (lane & 15);
      bf16x8 pa0 = *(const bf16x8*)(Ps + parow*LKV      + kSlot);
      bf16x8 pa1 = *(const bf16x8*)(Ps + parow*LKV + 32 + kSlot);
      #pragma unroll
      for (int n = 0; n < 4; ++n) {
        int vrow = n*16 + (lane & 15);
        bf16x8 bv0 = *(const bf16x8*)(Vts + vrow*LKV      + kSlot);
        bf16x8 bv1 = *(const bf16x8*)(Vts + vrow*LKV + 32 + kSlot);
        oacc[n] = __builtin_amdgcn_mfma_f32_16x16x32_bf16(pa0, bv0, oacc[n], 0, 0, 0);
        oacc[n] = __builtin_amdgcn_mfma_f32_16x16x32_bf16(pa1, bv1, oacc[n], 0, 0, 0);
      }
    }

    // epilogue: O /= l -> bf16 [B,T,C]
    const int tg = q0 + wid*16 + myrow4;
    #pragma unroll
    for (int n = 0; n < 4; ++n) {
      int ch = h*64 + n*16 + (lane & 15);
      #pragma unroll
      for (int j = 0; j < 4; ++j) {
        float o = oacc[n][j] / l_r[j];
        Oa[((size_t)(b*T_ + tg + j)) * C_ + ch] = (bf16)o;
      }
    }
  }
}

// ---------------------------------------------------------------------------
extern "C" void kernel_launch(void* const* d_in, const int* in_sizes, int n_in,
                              void* d_out, int out_size, void* d_ws, size_t ws_size,
                              hipStream_t stream) {
  const float* x  = (const float*)d_in[0];
  const float* wq = (const float*)d_in[1];
  const float* wk = (const float*)d_in[2];
  const float* wv = (const float*)d_in[3];
  const float* wo = (const float*)d_in[4];

  bf16* q  = (bf16*)d_ws;                    // [B,H,T,D] bf16
  bf16* k  = q  + (size_t)M_ * C_;
  bf16* v  = k  + (size_t)M_ * C_;           // [B,H,D,T] bf16 (transposed)
  bf16* aoStage = (bf16*)d_out;              // stage attn out in d_out (bf16)

  dim3 blk(256);
  // QKV projections: x(f32) @ W^T(f32) -> bf16 Q,K [B,H,T,D]; V [B,H,D,T]
  gemm_nt<0><<<dim3(C_/128, M_/128, 3), blk, 0, stream>>>(x, wq, wk, wv, q, k, v, C_);
  // causal flash attention (paired q-tiles) -> bf16 [B,T,C] staged in d_out
  attn_fwd<<<dim3(16, B_*H_), blk, 0, stream>>>(q, k, v, aoStage);
  // move staged ao into ws (q region dead after attention)
  hipMemcpyAsync(q, aoStage, (size_t)M_ * C_ * sizeof(bf16),
                 hipMemcpyDeviceToDevice, stream);
  // output projection: ao(bf16) @ wo^T(f32) -> f32 d_out
  gemm_nt<1><<<dim3(C_/128, M_/128, 1), blk, 0, stream>>>(q, wo, nullptr, nullptr,
                                                          d_out, nullptr, nullptr, C_);
}

// Round 9
// 164.976 us; speedup vs baseline: 1.3133x; 1.0416x over previous
//
#include <hip/hip_runtime.h>
#include <hip/hip_bf16.h>

#define B_ 2
#define T_ 2048
#define C_ 1024
#define H_ 16
#define D_ 64
#define M_ (B_*T_)          // 4096 rows
#define SCALE_ 0.125f       // 1/sqrt(64)
#define NEG_ (-1e30f)

typedef __bf16 bf16;
typedef __bf16 bf16x8 __attribute__((ext_vector_type(8)));
typedef float  f32x4  __attribute__((ext_vector_type(4)));

__device__ __forceinline__ bf16x8 cvt8(f32x4 a, f32x4 b) {
  bf16x8 r;
  #pragma unroll
  for (int i = 0; i < 4; ++i) { r[i] = (bf16)a[i]; r[i+4] = (bf16)b[i]; }
  return r;
}

// ---------------------------------------------------------------------------
// NT GEMM (MFMA): C[m,n] = sum_k A[m,k] * W[n,k]. 128x128 tile, BK=32, 4 waves.
// OUTMODE 0: A = f32 x; OUT bf16; z=0 -> Q*SCALE [B,H,T,D]; z=1 -> K [B,H,T,D];
//            z=2 -> V^T [B,H,D,T]
// OUTMODE 1: A = bf16 ao; OUT = f32 [M,C]  (final output)
// ---------------------------------------------------------------------------
#define LDK 40

template<int OUTMODE>
__global__ __launch_bounds__(256)
void gemm_nt(const void* __restrict__ Av,
             const float* __restrict__ W0, const float* __restrict__ W1,
             const float* __restrict__ W2,
             void* __restrict__ O0v, void* __restrict__ O1v, void* __restrict__ O2v,
             int K) {
  __shared__ __align__(16) bf16 As[128*LDK];
  __shared__ __align__(16) bf16 Bs[128*LDK];

  const float* W = W0;
  void* Ov = O0v;
  bool vtrans = false;
  float oscale = 1.0f;
  if constexpr (OUTMODE == 0) {
    if (blockIdx.z == 0)      { oscale = SCALE_; }                 // Q pre-scaled
    else if (blockIdx.z == 1) { W = W1; Ov = O1v; }
    else                      { W = W2; Ov = O2v; vtrans = true; }
  }

  const int m0 = blockIdx.y * 128, n0 = blockIdx.x * 128;
  const int tid = threadIdx.x, wid = tid >> 6, lane = tid & 63;
  const int wm = wid >> 1, wn = wid & 1;

  f32x4 acc[4][4] = {};

  const int sr = tid >> 2, skc = tid & 3;
  const float* Bg = W + (size_t)(n0 + sr) * K + skc*8;

  const float* AgF = nullptr; const bf16* AgH = nullptr;
  if constexpr (OUTMODE == 0) AgF = (const float*)Av + (size_t)(m0 + sr) * K + skc*8;
  else                        AgH = (const bf16*)Av  + (size_t)(m0 + sr) * K + skc*8;

  const int amRow = wm*64 + (lane & 15);
  const int bnRow = wn*64 + (lane & 15);
  const int kSlot = (lane >> 4) * 8;

  for (int k0 = 0; k0 < K; k0 += 32) {
    bf16x8 a0, a1;
    if constexpr (OUTMODE == 0) {
      a0 = cvt8(*(const f32x4*)(AgF + k0),
                *(const f32x4*)(AgF + k0 + 4));
      a1 = cvt8(*(const f32x4*)(AgF + (size_t)64*K + k0),
                *(const f32x4*)(AgF + (size_t)64*K + k0 + 4));
    } else {
      a0 = *(const bf16x8*)(AgH + k0);
      a1 = *(const bf16x8*)(AgH + (size_t)64*K + k0);
    }
    bf16x8 b0 = cvt8(*(const f32x4*)(Bg + k0),
                     *(const f32x4*)(Bg + k0 + 4));
    bf16x8 b1 = cvt8(*(const f32x4*)(Bg + (size_t)64*K + k0),
                     *(const f32x4*)(Bg + (size_t)64*K + k0 + 4));

    __syncthreads();
    *(bf16x8*)(As + sr*LDK        + skc*8) = a0;
    *(bf16x8*)(As + (sr+64)*LDK   + skc*8) = a1;
    *(bf16x8*)(Bs + sr*LDK        + skc*8) = b0;
    *(bf16x8*)(Bs + (sr+64)*LDK   + skc*8) = b1;
    __syncthreads();

    bf16x8 af[4], bfr[4];
    #pragma unroll
    for (int i = 0; i < 4; ++i) {
      af[i]  = *(const bf16x8*)(As + (amRow + i*16)*LDK + kSlot);
      bfr[i] = *(const bf16x8*)(Bs + (bnRow + i*16)*LDK + kSlot);
    }
    #pragma unroll
    for (int i = 0; i < 4; ++i)
      #pragma unroll
      for (int j = 0; j < 4; ++j)
        acc[i][j] = __builtin_amdgcn_mfma_f32_16x16x32_bf16(af[i], bfr[j], acc[i][j], 0, 0, 0);
  }

  // epilogue: C/D layout col=lane&15, row=(lane>>4)*4+reg
  const int rBase = m0 + wm*64 + (lane >> 4) * 4;
  const int cBase = n0 + wn*64 + (lane & 15);
  #pragma unroll
  for (int fm = 0; fm < 4; ++fm) {
    #pragma unroll
    for (int fn = 0; fn < 4; ++fn) {
      #pragma unroll
      for (int j = 0; j < 4; ++j) {
        int m = rBase + fm*16 + j;
        int n = cBase + fn*16;
        if constexpr (OUTMODE == 0) {
          int b = m >> 11, t = m & 2047, h = n >> 6, d = n & 63;
          size_t idx = vtrans ? (((size_t)(b*H_ + h) * D_ + d) * T_ + t)    // V^T [B,H,D,T]
                              : (((size_t)(b*H_ + h) * T_ + t) * D_ + d);  // Q,K [B,H,T,D]
          ((bf16*)Ov)[idx] = (bf16)(acc[fm][fn][j] * oscale);
        } else {
          ((float*)Ov)[(size_t)m * C_ + n] = acc[fm][fn][j];   // f32 final output
        }
      }
    }
  }
}

// ---------------------------------------------------------------------------
// Flash attention, causal. 1D grid of 1024 blocks, one 64-row q-tile each.
// Mapping: id -> qt = 31 - id/32 (heavy blocks dispatch first, LPT schedule),
//          bh = id & 31 (XCD x gets bh === x mod 8 -> K/V working set 2MB/XCD).
// 4 waves x 16 q-rows. Q pre-scaled by 1/sqrt(D). V pre-transposed [B,H,D,T].
// ---------------------------------------------------------------------------
#define LKV 72

__global__ __launch_bounds__(256)
void attn_fwd(const bf16* __restrict__ Q, const bf16* __restrict__ Km,
              const bf16* __restrict__ Vt, bf16* __restrict__ Oa) {
  __shared__ __align__(16) bf16 Ks [64*LKV];   // [kv][d]
  __shared__ __align__(16) bf16 Vts[64*LKV];   // [d][kv]
  __shared__ __align__(16) bf16 Ps [64*LKV];   // [q][kv] (wave-private rows)

  const int id = blockIdx.x;
  const int qt = 31 - (id >> 5);
  const int bh = id & 31;
  const int q0 = qt * 64;
  const int tid = threadIdx.x, wid = tid >> 6, lane = tid & 63;

  const bf16* Qb = Q  + (size_t)bh * T_ * D_;
  const bf16* Kb = Km + (size_t)bh * T_ * D_;
  const bf16* Vb = Vt + (size_t)bh * D_ * T_;  // [D,T]

  const int ksr = tid >> 3, kskc = tid & 7;
  const int myrow4 = (lane >> 4) * 4;
  const int kSlot = (lane >> 4) * 8;
  const int b = bh >> 4, h = bh & 15;

  const int qrow = q0 + wid*16 + (lane & 15);
  bf16x8 aq0 = *(const bf16x8*)(Qb + (size_t)qrow*64 +      (lane >> 4)*8);
  bf16x8 aq1 = *(const bf16x8*)(Qb + (size_t)qrow*64 + 32 + (lane >> 4)*8);

  f32x4 oacc[4] = {};
  float m_r[4], l_r[4];
  #pragma unroll
  for (int j = 0; j < 4; ++j) { m_r[j] = NEG_; l_r[j] = 0.f; }

  const int qg = q0 + wid*16 + myrow4;

  for (int kt = 0; kt <= qt; ++kt) {
    const int kv0 = kt * 64;

    // prefetch K and V^T tiles to registers (linear row copies)
    bf16x8 kv_a = *(const bf16x8*)(Kb + (size_t)(kv0 + ksr)*64      + kskc*8);
    bf16x8 kv_b = *(const bf16x8*)(Kb + (size_t)(kv0 + ksr + 32)*64 + kskc*8);
    bf16x8 vt_a = *(const bf16x8*)(Vb + (size_t)(ksr     )*T_ + kv0 + kskc*8);
    bf16x8 vt_b = *(const bf16x8*)(Vb + (size_t)(ksr + 32)*T_ + kv0 + kskc*8);

    __syncthreads();   // previous iteration's LDS reads complete

    *(bf16x8*)(Ks  + ksr*LKV      + kskc*8) = kv_a;
    *(bf16x8*)(Ks  + (ksr+32)*LKV + kskc*8) = kv_b;
    *(bf16x8*)(Vts + ksr*LKV      + kskc*8) = vt_a;
    *(bf16x8*)(Vts + (ksr+32)*LKV + kskc*8) = vt_b;
    __syncthreads();

    // S = Q K^T (Q pre-scaled)
    f32x4 s[4];
    #pragma unroll
    for (int n = 0; n < 4; ++n) {
      int row = n*16 + (lane & 15);
      bf16x8 bk0 = *(const bf16x8*)(Ks + row*LKV      + kSlot);
      bf16x8 bk1 = *(const bf16x8*)(Ks + row*LKV + 32 + kSlot);
      f32x4 a = {};
      a = __builtin_amdgcn_mfma_f32_16x16x32_bf16(aq0, bk0, a, 0, 0, 0);
      a = __builtin_amdgcn_mfma_f32_16x16x32_bf16(aq1, bk1, a, 0, 0, 0);
      s[n] = a;
    }

    // online softmax; causal mask only on the diagonal tile
    const bool diag = (kt == qt);
    #pragma unroll
    for (int j = 0; j < 4; ++j) {
      float pm = NEG_;
      if (diag) {
        #pragma unroll
        for (int n = 0; n < 4; ++n) {
          int kvg = kv0 + n*16 + (lane & 15);
          float sv = (kvg <= qg + j) ? s[n][j] : NEG_;
          s[n][j] = sv;
          pm = fmaxf(pm, sv);
        }
      } else {
        #pragma unroll
        for (int n = 0; n < 4; ++n) pm = fmaxf(pm, s[n][j]);
      }
      pm = fmaxf(pm, __shfl_xor(pm, 1));
      pm = fmaxf(pm, __shfl_xor(pm, 2));
      pm = fmaxf(pm, __shfl_xor(pm, 4));
      pm = fmaxf(pm, __shfl_xor(pm, 8));
      float mnew = fmaxf(m_r[j], pm);
      float scold = __expf(m_r[j] - mnew);
      float ps = 0.f;
      #pragma unroll
      for (int n = 0; n < 4; ++n) {
        float p = __expf(s[n][j] - mnew);
        s[n][j] = p;
        ps += p;
      }
      ps += __shfl_xor(ps, 1);
      ps += __shfl_xor(ps, 2);
      ps += __shfl_xor(ps, 4);
      ps += __shfl_xor(ps, 8);
      l_r[j] = l_r[j] * scold + ps;
      m_r[j] = mnew;
      #pragma unroll
      for (int n = 0; n < 4; ++n) oacc[n][j] *= scold;
    }

    // P -> LDS (wave-private rows): wave-level wait suffices
    #pragma unroll
    for (int n = 0; n < 4; ++n) {
      #pragma unroll
      for (int j = 0; j < 4; ++j) {
        int prow = wid*16 + myrow4 + j;
        Ps[prow*LKV + n*16 + (lane & 15)] = (bf16)s[n][j];
      }
    }
    asm volatile("s_waitcnt lgkmcnt(0)" ::: "memory");
    __builtin_amdgcn_sched_barrier(0);

    int parow = wid*16 + (lane & 15);
    bf16x8 pa0 = *(const bf16x8*)(Ps + parow*LKV      + kSlot);
    bf16x8 pa1 = *(const bf16x8*)(Ps + parow*LKV + 32 + kSlot);
    #pragma unroll
    for (int n = 0; n < 4; ++n) {
      int vrow = n*16 + (lane & 15);
      bf16x8 bv0 = *(const bf16x8*)(Vts + vrow*LKV      + kSlot);
      bf16x8 bv1 = *(const bf16x8*)(Vts + vrow*LKV + 32 + kSlot);
      oacc[n] = __builtin_amdgcn_mfma_f32_16x16x32_bf16(pa0, bv0, oacc[n], 0, 0, 0);
      oacc[n] = __builtin_amdgcn_mfma_f32_16x16x32_bf16(pa1, bv1, oacc[n], 0, 0, 0);
    }
  }

  // epilogue: O /= l -> bf16 [B,T,C]
  const int tg = q0 + wid*16 + myrow4;
  #pragma unroll
  for (int n = 0; n < 4; ++n) {
    int ch = h*64 + n*16 + (lane & 15);
    #pragma unroll
    for (int j = 0; j < 4; ++j) {
      float o = oacc[n][j] / l_r[j];
      Oa[((size_t)(b*T_ + tg + j)) * C_ + ch] = (bf16)o;
    }
  }
}

// ---------------------------------------------------------------------------
extern "C" void kernel_launch(void* const* d_in, const int* in_sizes, int n_in,
                              void* d_out, int out_size, void* d_ws, size_t ws_size,
                              hipStream_t stream) {
  const float* x  = (const float*)d_in[0];
  const float* wq = (const float*)d_in[1];
  const float* wk = (const float*)d_in[2];
  const float* wv = (const float*)d_in[3];
  const float* wo = (const float*)d_in[4];

  bf16* q  = (bf16*)d_ws;                    // [B,H,T,D] bf16 (pre-scaled)
  bf16* k  = q  + (size_t)M_ * C_;
  bf16* v  = k  + (size_t)M_ * C_;           // [B,H,D,T] bf16 (transposed)
  bf16* aoStage = (bf16*)d_out;              // stage attn out in d_out (bf16)

  dim3 blk(256);
  // QKV projections: x(f32) @ W^T(f32) -> bf16 Q*SCALE,K [B,H,T,D]; V^T [B,H,D,T]
  gemm_nt<0><<<dim3(C_/128, M_/128, 3), blk, 0, stream>>>(x, wq, wk, wv, q, k, v, C_);
  // causal flash attention (heavy-first, XCD-coherent) -> bf16 [B,T,C] in d_out
  attn_fwd<<<dim3(1024), blk, 0, stream>>>(q, k, v, aoStage);
  // move staged ao into ws (q region dead after attention)
  hipMemcpyAsync(q, aoStage, (size_t)M_ * C_ * sizeof(bf16),
                 hipMemcpyDeviceToDevice, stream);
  // output projection: ao(bf16) @ wo^T(f32) -> f32 d_out
  gemm_nt<1><<<dim3(C_/128, M_/128, 1), blk, 0, stream>>>(q, wo, nullptr, nullptr,
                                                          d_out, nullptr, nullptr, C_);
}

// Round 10
// 139.668 us; speedup vs baseline: 1.5513x; 1.1812x over previous
//
#include <hip/hip_runtime.h>
#include <hip/hip_bf16.h>

#define B_ 2
#define T_ 2048
#define C_ 1024
#define H_ 16
#define D_ 64
#define M_ (B_*T_)          // 4096 rows
#define SCALE_ 0.125f       // 1/sqrt(64)
#define LOG2E_ 1.44269504f
#define NEG_ (-1e30f)
#define THR_ 8.0f           // defer-max threshold (log2 units): P <= 256

typedef __bf16 bf16;
typedef __bf16 bf16x4 __attribute__((ext_vector_type(4)));
typedef __bf16 bf16x8 __attribute__((ext_vector_type(8)));
typedef float  f32x4  __attribute__((ext_vector_type(4)));

__device__ __forceinline__ bf16x8 cvt8(f32x4 a, f32x4 b) {
  bf16x8 r;
  #pragma unroll
  for (int i = 0; i < 4; ++i) { r[i] = (bf16)a[i]; r[i+4] = (bf16)b[i]; }
  return r;
}

// ---------------------------------------------------------------------------
// NT GEMM (MFMA): C[m,n] = sum_k A[m,k] * W[n,k]. 128x128 tile, BK=32, 4 waves.
// OUTMODE 0: A = f32 x; OUT bf16; z=0 -> Q*(SCALE*log2e) [B,H,T,D];
//            z=1 -> K [B,H,T,D]; z=2 -> V^T [B,H,D,T]
// OUTMODE 1: A = bf16 ao; OUT = f32 [M,C]  (final output)
// ---------------------------------------------------------------------------
#define LDK 40

template<int OUTMODE>
__global__ __launch_bounds__(256)
void gemm_nt(const void* __restrict__ Av,
             const float* __restrict__ W0, const float* __restrict__ W1,
             const float* __restrict__ W2,
             void* __restrict__ O0v, void* __restrict__ O1v, void* __restrict__ O2v,
             int K) {
  __shared__ __align__(16) bf16 As[128*LDK];
  __shared__ __align__(16) bf16 Bs[128*LDK];

  const float* W = W0;
  void* Ov = O0v;
  bool vtrans = false;
  float oscale = 1.0f;
  if constexpr (OUTMODE == 0) {
    if (blockIdx.z == 0)      { oscale = SCALE_ * LOG2E_; }        // Q pre-scaled
    else if (blockIdx.z == 1) { W = W1; Ov = O1v; }
    else                      { W = W2; Ov = O2v; vtrans = true; }
  }

  const int m0 = blockIdx.y * 128, n0 = blockIdx.x * 128;
  const int tid = threadIdx.x, wid = tid >> 6, lane = tid & 63;
  const int wm = wid >> 1, wn = wid & 1;

  f32x4 acc[4][4] = {};

  const int sr = tid >> 2, skc = tid & 3;
  const float* Bg = W + (size_t)(n0 + sr) * K + skc*8;

  const float* AgF = nullptr; const bf16* AgH = nullptr;
  if constexpr (OUTMODE == 0) AgF = (const float*)Av + (size_t)(m0 + sr) * K + skc*8;
  else                        AgH = (const bf16*)Av  + (size_t)(m0 + sr) * K + skc*8;

  const int amRow = wm*64 + (lane & 15);
  const int bnRow = wn*64 + (lane & 15);
  const int kSlot = (lane >> 4) * 8;

  for (int k0 = 0; k0 < K; k0 += 32) {
    bf16x8 a0, a1;
    if constexpr (OUTMODE == 0) {
      a0 = cvt8(*(const f32x4*)(AgF + k0),
                *(const f32x4*)(AgF + k0 + 4));
      a1 = cvt8(*(const f32x4*)(AgF + (size_t)64*K + k0),
                *(const f32x4*)(AgF + (size_t)64*K + k0 + 4));
    } else {
      a0 = *(const bf16x8*)(AgH + k0);
      a1 = *(const bf16x8*)(AgH + (size_t)64*K + k0);
    }
    bf16x8 b0 = cvt8(*(const f32x4*)(Bg + k0),
                     *(const f32x4*)(Bg + k0 + 4));
    bf16x8 b1 = cvt8(*(const f32x4*)(Bg + (size_t)64*K + k0),
                     *(const f32x4*)(Bg + (size_t)64*K + k0 + 4));

    __syncthreads();
    *(bf16x8*)(As + sr*LDK        + skc*8) = a0;
    *(bf16x8*)(As + (sr+64)*LDK   + skc*8) = a1;
    *(bf16x8*)(Bs + sr*LDK        + skc*8) = b0;
    *(bf16x8*)(Bs + (sr+64)*LDK   + skc*8) = b1;
    __syncthreads();

    bf16x8 af[4], bfr[4];
    #pragma unroll
    for (int i = 0; i < 4; ++i) {
      af[i]  = *(const bf16x8*)(As + (amRow + i*16)*LDK + kSlot);
      bfr[i] = *(const bf16x8*)(Bs + (bnRow + i*16)*LDK + kSlot);
    }
    #pragma unroll
    for (int i = 0; i < 4; ++i)
      #pragma unroll
      for (int j = 0; j < 4; ++j)
        acc[i][j] = __builtin_amdgcn_mfma_f32_16x16x32_bf16(af[i], bfr[j], acc[i][j], 0, 0, 0);
  }

  const int rBase = m0 + wm*64 + (lane >> 4) * 4;
  const int cBase = n0 + wn*64 + (lane & 15);
  #pragma unroll
  for (int fm = 0; fm < 4; ++fm) {
    #pragma unroll
    for (int fn = 0; fn < 4; ++fn) {
      #pragma unroll
      for (int j = 0; j < 4; ++j) {
        int m = rBase + fm*16 + j;
        int n = cBase + fn*16;
        if constexpr (OUTMODE == 0) {
          int b = m >> 11, t = m & 2047, h = n >> 6, d = n & 63;
          size_t idx = vtrans ? (((size_t)(b*H_ + h) * D_ + d) * T_ + t)
                              : (((size_t)(b*H_ + h) * T_ + t) * D_ + d);
          ((bf16*)Ov)[idx] = (bf16)(acc[fm][fn][j] * oscale);
        } else {
          ((float*)Ov)[(size_t)m * C_ + n] = acc[fm][fn][j];
        }
      }
    }
  }
}

// ---------------------------------------------------------------------------
// Flash attention, causal. Swapped-operand QK^T: lane owns q-row = lane&15,
// row reductions are in-register + 2 shuffles. Defer-max (THR=8 log2).
// Grid 1024: qt = 31 - id/32 (LPT), bh = id&31 (XCD-coherent).
// Q pre-scaled by SCALE*log2e. V pre-transposed [B,H,D,T].
// ---------------------------------------------------------------------------
#define LKV 72

__global__ __launch_bounds__(256)
void attn_fwd(const bf16* __restrict__ Q, const bf16* __restrict__ Km,
              const bf16* __restrict__ Vt, bf16* __restrict__ Oa) {
  __shared__ __align__(16) bf16 Ks [64*LKV];   // [kv][d]
  __shared__ __align__(16) bf16 Vts[64*LKV];   // [d][kv]
  __shared__ __align__(16) bf16 Ps [64*LKV];   // [q][kv] (wave-private rows)

  const int id = blockIdx.x;
  const int qt = 31 - (id >> 5);
  const int bh = id & 31;
  const int q0 = qt * 64;
  const int tid = threadIdx.x, wid = tid >> 6, lane = tid & 63;
  const int l15 = lane & 15;
  const int grp = lane >> 4;           // 0..3
  const int myrow4 = grp * 4;

  const bf16* Qb = Q  + (size_t)bh * T_ * D_;
  const bf16* Kb = Km + (size_t)bh * T_ * D_;
  const bf16* Vb = Vt + (size_t)bh * D_ * T_;  // [D,T]

  const int ksr = tid >> 3, kskc = tid & 7;
  const int kSlot = grp * 8;
  const int b = bh >> 4, h = bh & 15;

  const int qrow = q0 + wid*16 + l15;          // this lane's q-row (swapped layout)
  bf16x8 aq0 = *(const bf16x8*)(Qb + (size_t)qrow*64 +      grp*8);
  bf16x8 aq1 = *(const bf16x8*)(Qb + (size_t)qrow*64 + 32 + grp*8);

  f32x4 oacc[4] = {};
  float m_s = NEG_, l_s = 0.f;                 // per-lane (q = lane&15)

  // prologue: issue tile 0 loads
  bf16x8 kv_a = *(const bf16x8*)(Kb + (size_t)(ksr)*64      + kskc*8);
  bf16x8 kv_b = *(const bf16x8*)(Kb + (size_t)(ksr + 32)*64 + kskc*8);
  bf16x8 vt_a = *(const bf16x8*)(Vb + (size_t)(ksr     )*T_ + kskc*8);
  bf16x8 vt_b = *(const bf16x8*)(Vb + (size_t)(ksr + 32)*T_ + kskc*8);

  for (int kt = 0; kt <= qt; ++kt) {
    const int kv0 = kt * 64;

    __syncthreads();   // previous iteration's LDS reads complete
    *(bf16x8*)(Ks  + ksr*LKV      + kskc*8) = kv_a;
    *(bf16x8*)(Ks  + (ksr+32)*LKV + kskc*8) = kv_b;
    *(bf16x8*)(Vts + ksr*LKV      + kskc*8) = vt_a;
    *(bf16x8*)(Vts + (ksr+32)*LKV + kskc*8) = vt_b;
    __syncthreads();

    // issue next tile's loads early (hide HBM latency under compute)
    {
      const int kn = (kt < qt) ? kv0 + 64 : kv0;
      kv_a = *(const bf16x8*)(Kb + (size_t)(kn + ksr)*64      + kskc*8);
      kv_b = *(const bf16x8*)(Kb + (size_t)(kn + ksr + 32)*64 + kskc*8);
      vt_a = *(const bf16x8*)(Vb + (size_t)(ksr     )*T_ + kn + kskc*8);
      vt_b = *(const bf16x8*)(Vb + (size_t)(ksr + 32)*T_ + kn + kskc*8);
    }

    // S^T = K Q^T: s[n][j] = S[kv = kv0+n*16+myrow4+j][q = qrow]
    f32x4 s[4];
    #pragma unroll
    for (int n = 0; n < 4; ++n) {
      int row = n*16 + l15;
      bf16x8 bk0 = *(const bf16x8*)(Ks + row*LKV      + kSlot);
      bf16x8 bk1 = *(const bf16x8*)(Ks + row*LKV + 32 + kSlot);
      f32x4 a = {};
      a = __builtin_amdgcn_mfma_f32_16x16x32_bf16(bk0, aq0, a, 0, 0, 0);
      a = __builtin_amdgcn_mfma_f32_16x16x32_bf16(bk1, aq1, a, 0, 0, 0);
      s[n] = a;
    }

    // mask (diagonal tile only) + row max (in-register + 2 shuffles)
    float pmax = NEG_;
    if (kt == qt) {
      #pragma unroll
      for (int n = 0; n < 4; ++n)
        #pragma unroll
        for (int j = 0; j < 4; ++j) {
          int kvg = kv0 + n*16 + myrow4 + j;
          float sv = (kvg <= qrow) ? s[n][j] : NEG_;
          s[n][j] = sv;
          pmax = fmaxf(pmax, sv);
        }
    } else {
      #pragma unroll
      for (int n = 0; n < 4; ++n)
        #pragma unroll
        for (int j = 0; j < 4; ++j) pmax = fmaxf(pmax, s[n][j]);
    }
    pmax = fmaxf(pmax, __shfl_xor(pmax, 16));
    pmax = fmaxf(pmax, __shfl_xor(pmax, 32));

    // defer-max: rescale only when the bound would be exceeded
    if (__any(pmax > m_s + THR_)) {
      float mnew = fmaxf(m_s, pmax);
      float scold = __builtin_amdgcn_exp2f(m_s - mnew);
      m_s = mnew;
      l_s *= scold;
      #pragma unroll
      for (int j = 0; j < 4; ++j) {
        float scj = __shfl(scold, myrow4 + j);
        #pragma unroll
        for (int n = 0; n < 4; ++n) oacc[n][j] *= scj;
      }
    }

    // p = 2^(s - m); row sum; write P (4x b64, contiguous kv per lane)
    float ps = 0.f;
    #pragma unroll
    for (int n = 0; n < 4; ++n) {
      bf16x4 pw;
      #pragma unroll
      for (int j = 0; j < 4; ++j) {
        float p = __builtin_amdgcn_exp2f(s[n][j] - m_s);
        ps += p;
        pw[j] = (bf16)p;
      }
      *(bf16x4*)(Ps + (size_t)(wid*16 + l15)*LKV + n*16 + myrow4) = pw;
    }
    ps += __shfl_xor(ps, 16);
    ps += __shfl_xor(ps, 32);
    l_s += ps;

    asm volatile("s_waitcnt lgkmcnt(0)" ::: "memory");
    __builtin_amdgcn_sched_barrier(0);

    // O += P V  (P rows wave-private)
    int parow = wid*16 + l15;
    bf16x8 pa0 = *(const bf16x8*)(Ps + parow*LKV      + kSlot);
    bf16x8 pa1 = *(const bf16x8*)(Ps + parow*LKV + 32 + kSlot);
    #pragma unroll
    for (int n = 0; n < 4; ++n) {
      int vrow = n*16 + l15;
      bf16x8 bv0 = *(const bf16x8*)(Vts + vrow*LKV      + kSlot);
      bf16x8 bv1 = *(const bf16x8*)(Vts + vrow*LKV + 32 + kSlot);
      oacc[n] = __builtin_amdgcn_mfma_f32_16x16x32_bf16(pa0, bv0, oacc[n], 0, 0, 0);
      oacc[n] = __builtin_amdgcn_mfma_f32_16x16x32_bf16(pa1, bv1, oacc[n], 0, 0, 0);
    }
  }

  // epilogue: redistribute l to C-layout rows, divide, write [B,T,C]
  const int tg = q0 + wid*16 + myrow4;
  #pragma unroll
  for (int j = 0; j < 4; ++j) {
    float lj = __shfl(l_s, myrow4 + j);
    float inv = 1.f / lj;
    int trow = tg + j;
    #pragma unroll
    for (int n = 0; n < 4; ++n) {
      int ch = h*64 + n*16 + l15;
      Oa[((size_t)(b*T_ + trow)) * C_ + ch] = (bf16)(oacc[n][j] * inv);
    }
  }
}

// ---------------------------------------------------------------------------
extern "C" void kernel_launch(void* const* d_in, const int* in_sizes, int n_in,
                              void* d_out, int out_size, void* d_ws, size_t ws_size,
                              hipStream_t stream) {
  const float* x  = (const float*)d_in[0];
  const float* wq = (const float*)d_in[1];
  const float* wk = (const float*)d_in[2];
  const float* wv = (const float*)d_in[3];
  const float* wo = (const float*)d_in[4];

  bf16* q  = (bf16*)d_ws;                    // [B,H,T,D] bf16 (pre-scaled)
  bf16* k  = q  + (size_t)M_ * C_;
  bf16* v  = k  + (size_t)M_ * C_;           // [B,H,D,T] bf16 (transposed)
  bf16* aoStage = (bf16*)d_out;              // stage attn out in d_out (bf16)

  dim3 blk(256);
  gemm_nt<0><<<dim3(C_/128, M_/128, 3), blk, 0, stream>>>(x, wq, wk, wv, q, k, v, C_);
  attn_fwd<<<dim3(1024), blk, 0, stream>>>(q, k, v, aoStage);
  hipMemcpyAsync(q, aoStage, (size_t)M_ * C_ * sizeof(bf16),
                 hipMemcpyDeviceToDevice, stream);
  gemm_nt<1><<<dim3(C_/128, M_/128, 1), blk, 0, stream>>>(q, wo, nullptr, nullptr,
                                                          d_out, nullptr, nullptr, C_);
}

// Round 11
// 134.429 us; speedup vs baseline: 1.6117x; 1.0390x over previous
//
#include <hip/hip_runtime.h>
#include <hip/hip_bf16.h>

#define B_ 2
#define T_ 2048
#define C_ 1024
#define H_ 16
#define D_ 64
#define M_ (B_*T_)          // 4096 rows
#define SCALE_ 0.125f       // 1/sqrt(64)
#define LOG2E_ 1.44269504f
#define NEG_ (-1e30f)
#define THR_ 8.0f           // defer-max threshold (log2 units)

typedef __bf16 bf16;
typedef __bf16 bf16x4 __attribute__((ext_vector_type(4)));
typedef __bf16 bf16x8 __attribute__((ext_vector_type(8)));
typedef float  f32x4  __attribute__((ext_vector_type(4)));

#define XB_ELEMS  ((size_t)M_*C_)        // 4,194,304
#define W_ELEMS   ((size_t)C_*C_)        // 1,048,576

__device__ __forceinline__ void glds16(const void* g, void* l) {
  __builtin_amdgcn_global_load_lds((const __attribute__((address_space(1))) void*)g,
                                   (__attribute__((address_space(3))) void*)l,
                                   16, 0, 0);
}

// ---------------------------------------------------------------------------
// f32 -> bf16 conversion pass. Block = 2048 elements (256 thr x 8).
// Blocks [0,2048): x -> out[0..). [2048,2560): wq. ... [3584,4096): wo.
// ---------------------------------------------------------------------------
__global__ __launch_bounds__(256)
void cvt5(const float* __restrict__ x,  const float* __restrict__ wq,
          const float* __restrict__ wk, const float* __restrict__ wv,
          const float* __restrict__ wo, bf16* __restrict__ out) {
  int bid = blockIdx.x;
  const float* src; bf16* dst; size_t off;
  if (bid < 2048)      { src = x;  dst = out;                         off = (size_t)bid*2048; }
  else if (bid < 2560) { src = wq; dst = out + XB_ELEMS;              off = (size_t)(bid-2048)*2048; }
  else if (bid < 3072) { src = wk; dst = out + XB_ELEMS +   W_ELEMS;  off = (size_t)(bid-2560)*2048; }
  else if (bid < 3584) { src = wv; dst = out + XB_ELEMS + 2*W_ELEMS;  off = (size_t)(bid-3072)*2048; }
  else                 { src = wo; dst = out + XB_ELEMS + 3*W_ELEMS;  off = (size_t)(bid-3584)*2048; }
  size_t i = off + (size_t)threadIdx.x * 8;
  f32x4 lo = *(const f32x4*)(src + i);
  f32x4 hi = *(const f32x4*)(src + i + 4);
  bf16x8 r;
  #pragma unroll
  for (int t = 0; t < 4; ++t) { r[t] = (bf16)lo[t]; r[t+4] = (bf16)hi[t]; }
  *(bf16x8*)(dst + i) = r;
}

// ---------------------------------------------------------------------------
// NT GEMM (MFMA, pure bf16, global_load_lds staging — m97 recipe):
// C[m,n] = sum_k A[m,k] * W[n,k]. 128x128 tile, BK=32, 4 waves, linear LDS.
// OUTMODE 0: OUT bf16; z=0 -> Q*(SCALE*log2e) [B,H,T,D]; z=1 -> K [B,H,T,D];
//            z=2 -> V^T [B,H,D,T]
// OUTMODE 1: OUT = f32 [M,C]  (final output)
// ---------------------------------------------------------------------------
template<int OUTMODE>
__global__ __launch_bounds__(256)
void gemm_nt(const bf16* __restrict__ Ab,
             const bf16* __restrict__ W0, const bf16* __restrict__ W1,
             const bf16* __restrict__ W2,
             void* __restrict__ O0v, void* __restrict__ O1v, void* __restrict__ O2v,
             int K) {
  __shared__ __align__(16) bf16 As[128*32];
  __shared__ __align__(16) bf16 Bs[128*32];

  const bf16* W = W0;
  void* Ov = O0v;
  bool vtrans = false;
  float oscale = 1.0f;
  if constexpr (OUTMODE == 0) {
    if (blockIdx.z == 0)      { oscale = SCALE_ * LOG2E_; }
    else if (blockIdx.z == 1) { W = W1; Ov = O1v; }
    else                      { W = W2; Ov = O2v; vtrans = true; }
  }

  const int m0 = blockIdx.y * 128, n0 = blockIdx.x * 128;
  const int tid = threadIdx.x, wid = tid >> 6, lane = tid & 63;
  const int wm = wid >> 1, wn = wid & 1;
  const int l15 = lane & 15, grp = lane >> 4;

  f32x4 acc[4][4] = {};

  // glds16 staging: chunk c (16 rows x 32k = 1KB); wave handles c0=wid, c1=wid+4.
  // lane l -> row lr = l>>2 within chunk, k-elem lk = (l&3)*8.
  const int lr = lane >> 2, lk = (lane & 3) * 8;
  const int c0 = wid, c1 = wid + 4;
  const bf16* Ag0 = Ab + (size_t)(m0 + c0*16 + lr) * K + lk;
  const bf16* Ag1 = Ab + (size_t)(m0 + c1*16 + lr) * K + lk;
  const bf16* Bg0 = W  + (size_t)(n0 + c0*16 + lr) * K + lk;
  const bf16* Bg1 = W  + (size_t)(n0 + c1*16 + lr) * K + lk;
  bf16* Al0 = As + c0*512; bf16* Al1 = As + c1*512;   // wave-uniform LDS bases
  bf16* Bl0 = Bs + c0*512; bf16* Bl1 = Bs + c1*512;

  const int amRow = wm*64 + l15;
  const int bnRow = wn*64 + l15;
  const int kSlot = grp * 8;

  for (int k0 = 0; k0 < K; k0 += 32) {
    __syncthreads();                    // prev iteration's LDS reads complete
    glds16(Ag0 + k0, Al0);
    glds16(Ag1 + k0, Al1);
    glds16(Bg0 + k0, Bl0);
    glds16(Bg1 + k0, Bl1);
    __syncthreads();                    // compiler drains vmcnt before barrier

    bf16x8 af[4], bfr[4];
    #pragma unroll
    for (int i = 0; i < 4; ++i) {
      af[i]  = *(const bf16x8*)(As + (amRow + i*16)*32 + kSlot);
      bfr[i] = *(const bf16x8*)(Bs + (bnRow + i*16)*32 + kSlot);
    }
    #pragma unroll
    for (int i = 0; i < 4; ++i)
      #pragma unroll
      for (int j = 0; j < 4; ++j)
        acc[i][j] = __builtin_amdgcn_mfma_f32_16x16x32_bf16(af[i], bfr[j], acc[i][j], 0, 0, 0);
  }

  // epilogue: C/D layout col=lane&15, row=(lane>>4)*4+reg
  const int rBase = m0 + wm*64 + grp * 4;
  const int cBase = n0 + wn*64 + l15;
  #pragma unroll
  for (int fm = 0; fm < 4; ++fm) {
    #pragma unroll
    for (int fn = 0; fn < 4; ++fn) {
      #pragma unroll
      for (int j = 0; j < 4; ++j) {
        int m = rBase + fm*16 + j;
        int n = cBase + fn*16;
        if constexpr (OUTMODE == 0) {
          int b = m >> 11, t = m & 2047, h = n >> 6, d = n & 63;
          size_t idx = vtrans ? (((size_t)(b*H_ + h) * D_ + d) * T_ + t)
                              : (((size_t)(b*H_ + h) * T_ + t) * D_ + d);
          ((bf16*)Ov)[idx] = (bf16)(acc[fm][fn][j] * oscale);
        } else {
          ((float*)Ov)[(size_t)m * C_ + n] = acc[fm][fn][j];
        }
      }
    }
  }
}

// ---------------------------------------------------------------------------
// Flash attention, causal (unchanged from round 10).
// ---------------------------------------------------------------------------
#define LKV 72

__global__ __launch_bounds__(256)
void attn_fwd(const bf16* __restrict__ Q, const bf16* __restrict__ Km,
              const bf16* __restrict__ Vt, bf16* __restrict__ Oa) {
  __shared__ __align__(16) bf16 Ks [64*LKV];
  __shared__ __align__(16) bf16 Vts[64*LKV];
  __shared__ __align__(16) bf16 Ps [64*LKV];

  const int id = blockIdx.x;
  const int qt = 31 - (id >> 5);
  const int bh = id & 31;
  const int q0 = qt * 64;
  const int tid = threadIdx.x, wid = tid >> 6, lane = tid & 63;
  const int l15 = lane & 15;
  const int grp = lane >> 4;
  const int myrow4 = grp * 4;

  const bf16* Qb = Q  + (size_t)bh * T_ * D_;
  const bf16* Kb = Km + (size_t)bh * T_ * D_;
  const bf16* Vb = Vt + (size_t)bh * D_ * T_;

  const int ksr = tid >> 3, kskc = tid & 7;
  const int kSlot = grp * 8;
  const int b = bh >> 4, h = bh & 15;

  const int qrow = q0 + wid*16 + l15;
  bf16x8 aq0 = *(const bf16x8*)(Qb + (size_t)qrow*64 +      grp*8);
  bf16x8 aq1 = *(const bf16x8*)(Qb + (size_t)qrow*64 + 32 + grp*8);

  f32x4 oacc[4] = {};
  float m_s = NEG_, l_s = 0.f;

  bf16x8 kv_a = *(const bf16x8*)(Kb + (size_t)(ksr)*64      + kskc*8);
  bf16x8 kv_b = *(const bf16x8*)(Kb + (size_t)(ksr + 32)*64 + kskc*8);
  bf16x8 vt_a = *(const bf16x8*)(Vb + (size_t)(ksr     )*T_ + kskc*8);
  bf16x8 vt_b = *(const bf16x8*)(Vb + (size_t)(ksr + 32)*T_ + kskc*8);

  for (int kt = 0; kt <= qt; ++kt) {
    const int kv0 = kt * 64;

    __syncthreads();
    *(bf16x8*)(Ks  + ksr*LKV      + kskc*8) = kv_a;
    *(bf16x8*)(Ks  + (ksr+32)*LKV + kskc*8) = kv_b;
    *(bf16x8*)(Vts + ksr*LKV      + kskc*8) = vt_a;
    *(bf16x8*)(Vts + (ksr+32)*LKV + kskc*8) = vt_b;
    __syncthreads();

    {
      const int kn = (kt < qt) ? kv0 + 64 : kv0;
      kv_a = *(const bf16x8*)(Kb + (size_t)(kn + ksr)*64      + kskc*8);
      kv_b = *(const bf16x8*)(Kb + (size_t)(kn + ksr + 32)*64 + kskc*8);
      vt_a = *(const bf16x8*)(Vb + (size_t)(ksr     )*T_ + kn + kskc*8);
      vt_b = *(const bf16x8*)(Vb + (size_t)(ksr + 32)*T_ + kn + kskc*8);
    }

    f32x4 s[4];
    #pragma unroll
    for (int n = 0; n < 4; ++n) {
      int row = n*16 + l15;
      bf16x8 bk0 = *(const bf16x8*)(Ks + row*LKV      + kSlot);
      bf16x8 bk1 = *(const bf16x8*)(Ks + row*LKV + 32 + kSlot);
      f32x4 a = {};
      a = __builtin_amdgcn_mfma_f32_16x16x32_bf16(bk0, aq0, a, 0, 0, 0);
      a = __builtin_amdgcn_mfma_f32_16x16x32_bf16(bk1, aq1, a, 0, 0, 0);
      s[n] = a;
    }

    float pmax = NEG_;
    if (kt == qt) {
      #pragma unroll
      for (int n = 0; n < 4; ++n)
        #pragma unroll
        for (int j = 0; j < 4; ++j) {
          int kvg = kv0 + n*16 + myrow4 + j;
          float sv = (kvg <= qrow) ? s[n][j] : NEG_;
          s[n][j] = sv;
          pmax = fmaxf(pmax, sv);
        }
    } else {
      #pragma unroll
      for (int n = 0; n < 4; ++n)
        #pragma unroll
        for (int j = 0; j < 4; ++j) pmax = fmaxf(pmax, s[n][j]);
    }
    pmax = fmaxf(pmax, __shfl_xor(pmax, 16));
    pmax = fmaxf(pmax, __shfl_xor(pmax, 32));

    if (__any(pmax > m_s + THR_)) {
      float mnew = fmaxf(m_s, pmax);
      float scold = __builtin_amdgcn_exp2f(m_s - mnew);
      m_s = mnew;
      l_s *= scold;
      #pragma unroll
      for (int j = 0; j < 4; ++j) {
        float scj = __shfl(scold, myrow4 + j);
        #pragma unroll
        for (int n = 0; n < 4; ++n) oacc[n][j] *= scj;
      }
    }

    float ps = 0.f;
    #pragma unroll
    for (int n = 0; n < 4; ++n) {
      bf16x4 pw;
      #pragma unroll
      for (int j = 0; j < 4; ++j) {
        float p = __builtin_amdgcn_exp2f(s[n][j] - m_s);
        ps += p;
        pw[j] = (bf16)p;
      }
      *(bf16x4*)(Ps + (size_t)(wid*16 + l15)*LKV + n*16 + myrow4) = pw;
    }
    ps += __shfl_xor(ps, 16);
    ps += __shfl_xor(ps, 32);
    l_s += ps;

    asm volatile("s_waitcnt lgkmcnt(0)" ::: "memory");
    __builtin_amdgcn_sched_barrier(0);

    int parow = wid*16 + l15;
    bf16x8 pa0 = *(const bf16x8*)(Ps + parow*LKV      + kSlot);
    bf16x8 pa1 = *(const bf16x8*)(Ps + parow*LKV + 32 + kSlot);
    #pragma unroll
    for (int n = 0; n < 4; ++n) {
      int vrow = n*16 + l15;
      bf16x8 bv0 = *(const bf16x8*)(Vts + vrow*LKV      + kSlot);
      bf16x8 bv1 = *(const bf16x8*)(Vts + vrow*LKV + 32 + kSlot);
      oacc[n] = __builtin_amdgcn_mfma_f32_16x16x32_bf16(pa0, bv0, oacc[n], 0, 0, 0);
      oacc[n] = __builtin_amdgcn_mfma_f32_16x16x32_bf16(pa1, bv1, oacc[n], 0, 0, 0);
    }
  }

  const int tg = q0 + wid*16 + myrow4;
  #pragma unroll
  for (int j = 0; j < 4; ++j) {
    float lj = __shfl(l_s, myrow4 + j);
    float inv = 1.f / lj;
    int trow = tg + j;
    #pragma unroll
    for (int n = 0; n < 4; ++n) {
      int ch = h*64 + n*16 + l15;
      Oa[((size_t)(b*T_ + trow)) * C_ + ch] = (bf16)(oacc[n][j] * inv);
    }
  }
}

// ---------------------------------------------------------------------------
extern "C" void kernel_launch(void* const* d_in, const int* in_sizes, int n_in,
                              void* d_out, int out_size, void* d_ws, size_t ws_size,
                              hipStream_t stream) {
  const float* x  = (const float*)d_in[0];
  const float* wq = (const float*)d_in[1];
  const float* wk = (const float*)d_in[2];
  const float* wv = (const float*)d_in[3];
  const float* wo = (const float*)d_in[4];

  bf16* q  = (bf16*)d_ws;                    // [B,H,T,D] bf16 (Q pre-scaled)
  bf16* k  = q  + XB_ELEMS;
  bf16* v  = k  + XB_ELEMS;                  // [B,H,D,T] bf16 (transposed)

  bf16* cvtbuf = (bf16*)d_out;               // bf16 staging inside d_out
  bf16* xb  = cvtbuf;                        // [M,K] bf16
  bf16* wqb = cvtbuf + XB_ELEMS;
  bf16* wkb = wqb + W_ELEMS;
  bf16* wvb = wkb + W_ELEMS;
  bf16* wob = wvb + W_ELEMS;                 // exactly fills d_out

  dim3 blk(256);
  // 0) convert all f32 inputs to bf16 (into d_out)
  cvt5<<<dim3(4096), blk, 0, stream>>>(x, wq, wk, wv, wo, cvtbuf);
  // 1) QKV projections (pure bf16, glds16): xb @ W^T -> q,k,v
  gemm_nt<0><<<dim3(C_/128, M_/128, 3), blk, 0, stream>>>(xb, wqb, wkb, wvb,
                                                          q, k, v, C_);
  // 2) causal flash attention -> ao bf16 [B,T,C] into xb slot (x dead)
  attn_fwd<<<dim3(1024), blk, 0, stream>>>(q, k, v, xb);
  // 3) relocate ao and wo_bf16 into ws (q,k slots dead after attention)
  hipMemcpyAsync(q, xb,  XB_ELEMS * sizeof(bf16), hipMemcpyDeviceToDevice, stream);
  hipMemcpyAsync(k, wob, W_ELEMS  * sizeof(bf16), hipMemcpyDeviceToDevice, stream);
  // 4) output projection: ao @ wo^T -> f32 d_out (no overlap with reads)
  gemm_nt<1><<<dim3(C_/128, M_/128, 1), blk, 0, stream>>>(q, k, nullptr, nullptr,
                                                          d_out, nullptr, nullptr, C_);
}